// Round 6
// baseline (391.488 us; speedup 1.0000x reference)
//
#include <hip/hip_runtime.h>

#define SAMPLES 128
#define HID 256
#define NEARV 0.1f
#define FARV 4.0f
#define DZ ((FARV - NEARV) / (SAMPLES - 1))
#define EPSV 1e-6f

typedef __attribute__((ext_vector_type(8))) short v8s;    // 8 x bf16
typedef __attribute__((ext_vector_type(4))) float v4f;    // 4 x fp32
typedef __attribute__((ext_vector_type(16))) float v16f;  // 16 x fp32

__device__ __forceinline__ unsigned short f2b(float f) {
  union { float f; unsigned u; } v; v.f = f;
  return (unsigned short)((v.u + 0x7fffu + ((v.u >> 16) & 1u)) >> 16);  // RNE
}

#if __has_builtin(__builtin_amdgcn_cvt_pk_bf16_f32)
typedef __bf16 bf2 __attribute__((ext_vector_type(2)));
__device__ __forceinline__ unsigned pk2(float a, float b) {
  union { bf2 v; unsigned u; } c;
  c.v = __builtin_amdgcn_cvt_pk_bf16_f32(a, b);
  return c.u;
}
#else
__device__ __forceinline__ unsigned pk2(float a, float b) {
  return (unsigned)f2b(a) | ((unsigned)f2b(b) << 16);
}
#endif

// R3's proven XOR-swizzled LDS address for the 128x256 bf16 activation buffer.
__device__ __forceinline__ int haddr(int m, int k) {
  return m * 256 + ((((k >> 3) ^ (m & 15)) << 3) | (k & 7));
}

// Merged pack kernel. Blocks 0-31: W2 -> 32x32x16 A-operand fragment-linear bf16
// (chunk nt*1024 + ks*64 + h*32 + r32 holds W2[k=ks*16+h*8 ..+8)][n=nt*32+r32]).
// Blocks 32-33: [Wsig | Wrgb(:256) | 0] (K=256,N=16) in 16x16x32 B-operand layout.
__global__ void pack(const float* __restrict__ W2, const float* __restrict__ Wsig,
                     const float* __restrict__ Wrgb,
                     unsigned short* __restrict__ w2p, unsigned short* __restrict__ hdp) {
  int b = blockIdx.x;
  if (b < 32) {
    int t = b * 256 + threadIdx.x;   // 0..8191
    int r32 = t & 31;
    int h   = (t >> 5) & 1;
    int ks  = (t >> 6) & 15;
    int nt  = t >> 10;
    int n  = nt * 32 + r32;
    int k0 = ks * 16 + h * 8;
#pragma unroll
    for (int j = 0; j < 8; ++j) w2p[t * 8 + j] = f2b(W2[(k0 + j) * 256 + n]);
  } else {
    int t = (b - 32) * 256 + threadIdx.x;   // 0..511
    int n = t & 15, q = (t >> 4) & 3, kt = t >> 6;
    int k0 = kt * 32 + q * 8;
#pragma unroll
    for (int j = 0; j < 8; ++j) {
      int k = k0 + j;
      float v = 0.f;
      if (n == 0)      v = Wsig[k];
      else if (n < 4)  v = Wrgb[k * 3 + (n - 1)];
      hdp[t * 8 + j] = f2b(v);
    }
  }
}

// Persistent: 512 blocks x 512 threads (8 waves), each block renders rpb rays.
// W2 A-fragments live in registers (128 VGPR/lane) for the whole block.
// (512,2): 256-VGPR cap -> 2 waves/SIMD, 1 block/CU.
__global__ __launch_bounds__(512, 2) void render(
    const float* __restrict__ cam, const float* __restrict__ rayv,
    const float* __restrict__ W1, const float* __restrict__ b1,
    const float* __restrict__ b2, const float* __restrict__ bsig,
    const float* __restrict__ Wrgb, const float* __restrict__ brgb,
    const unsigned short* __restrict__ W2p, const unsigned short* __restrict__ Hdp,
    float* __restrict__ out, int rpb) {
  __shared__ __align__(16) unsigned short smem[128 * 256 + 1024];  // 64KB act + 2KB fbH
  float* fbH = (float*)(smem + 128 * 256);   // [128][4] f32 head outputs

  const int tid  = threadIdx.x;
  const int lane = tid & 63;
  const int wv   = tid >> 6;        // 0..7
  const int l31  = lane & 31;
  const int half = lane >> 5;
  const int q    = lane >> 4;
  const int l16  = lane & 15;
  const int nsup = wv >> 1;         // 0..3: n base = nsup*64
  const int msup = wv & 1;          // 0..1: m base = msup*64

  // ---- persistent A-fragments: W2[:, nsup*64 .. +63] (32 KB/wave, once)
  v8s areg[32];                     // [ks][nt] -> areg[ks*2+nt], 128 VGPRs
  {
    const v8s* Ap = (const v8s*)W2p;
    const int abase = nsup * 2 * 1024 + half * 32 + l31;
#pragma unroll
    for (int ks = 0; ks < 16; ++ks) {
      areg[ks * 2 + 0] = Ap[abase + ks * 64];          // coalesced 1KB/wave
      areg[ks * 2 + 1] = Ap[abase + 1024 + ks * 64];
    }
  }

  // ---- layer-1 weights for this thread's 4 columns (hoisted, 16 VGPRs)
  const int n4 = (tid & 63) * 4;
  const int m0 = tid >> 6;          // 0..7
  const float4 wa = *(const float4*)(W1 + n4);
  const float4 wb = *(const float4*)(W1 + 256 + n4);
  const float4 wc = *(const float4*)(W1 + 512 + n4);
  const float4 bb = *(const float4*)(b1 + n4);

  for (int i = 0; i < rpb; ++i) {
    const int ray = blockIdx.x * rpb + i;

    // ---- per-ray geometry (block-uniform scalar loads)
    float rvx = rayv[ray * 3 + 0], rvy = rayv[ray * 3 + 1], rvz = rayv[ray * 3 + 2];
    float rn  = 1.0f / sqrtf(rvx * rvx + rvy * rvy + rvz * rvz);
    float rdx = rvx * rn, rdy = rvy * rn, rdz = rvz * rn;
    float cx = cam[ray * 3 + 0], cy = cam[ray * 3 + 1], cz = cam[ray * 3 + 2];

    // ---- Layer 1 (rank-2): h1[m][n] = relu(u[n] + z_m * v[n]) -> LDS
    {
      float4 u, v;
      u.x = bb.x + cx * wa.x + cy * wb.x + cz * wc.x;  v.x = rdx * wa.x + rdy * wb.x + rdz * wc.x;
      u.y = bb.y + cx * wa.y + cy * wb.y + cz * wc.y;  v.y = rdx * wa.y + rdy * wb.y + rdz * wc.y;
      u.z = bb.z + cx * wa.z + cy * wb.z + cz * wc.z;  v.z = rdx * wa.z + rdy * wb.z + rdz * wc.z;
      u.w = bb.w + cx * wa.w + cy * wb.w + cz * wc.w;  v.w = rdx * wa.w + rdy * wb.w + rdz * wc.w;
#pragma unroll
      for (int r = 0; r < 16; ++r) {
        int m = m0 + r * 8;
        float z = NEARV + DZ * (float)m;
        float h0 = fmaxf(u.x + z * v.x, 0.f);
        float h1 = fmaxf(u.y + z * v.y, 0.f);
        float h2 = fmaxf(u.z + z * v.z, 0.f);
        float h3 = fmaxf(u.w + z * v.w, 0.f);
        uint2 pk; pk.x = pk2(h0, h1); pk.y = pk2(h2, h3);
        *(uint2*)(smem + haddr(m, n4)) = pk;   // ds_write_b64
      }
    }
    __syncthreads();

    // ---- Layer 2 GEMM (swapped, 32x32x16): C'[n][m] = W2^T @ h1^T
    // A from registers, B (h1) from LDS. 64x64 per wave.
    v16f acc[2][2];   // [mt][nt]
#pragma unroll
    for (int a = 0; a < 2; ++a)
#pragma unroll
      for (int c = 0; c < 2; ++c) acc[a][c] = (v16f)(0.f);
    {
      const int mA = msup * 64 + l31;
      const unsigned short* bp = smem + mA * 256;   // b1 row = +32 -> +16384B imm
      const int mx = mA & 15;
#pragma unroll
      for (int ks = 0; ks < 16; ++ks) {
        int off = ((ks * 2 + half) ^ mx) << 3;
        v8s b0 = *(const v8s*)(bp + off);             // ds_read_b128
        v8s b1 = *(const v8s*)(bp + 32 * 256 + off);  // imm offset:16384
        acc[0][0] = __builtin_amdgcn_mfma_f32_32x32x16_bf16(areg[ks*2+0], b0, acc[0][0], 0, 0, 0);
        acc[0][1] = __builtin_amdgcn_mfma_f32_32x32x16_bf16(areg[ks*2+1], b0, acc[0][1], 0, 0, 0);
        acc[1][0] = __builtin_amdgcn_mfma_f32_32x32x16_bf16(areg[ks*2+0], b1, acc[1][0], 0, 0, 0);
        acc[1][1] = __builtin_amdgcn_mfma_f32_32x32x16_bf16(areg[ks*2+1], b1, acc[1][1], 0, 0, 0);
      }
    }
    __syncthreads();   // h1 reads done; smem reused for h2

    // ---- epilogue: lane holds C'[n][m], n = nsup*64 + nt*32 + g*8 + half*4 + r,
    // m = msup*64 + mt*32 + l31 -> packed b64 writes into [m][n] layout.
#pragma unroll
    for (int mt = 0; mt < 2; ++mt) {
      const int m = msup * 64 + mt * 32 + l31;
#pragma unroll
      for (int nt = 0; nt < 2; ++nt) {
        const int nb0 = nsup * 64 + nt * 32 + half * 4;
#pragma unroll
        for (int g = 0; g < 4; ++g) {
          int nb = nb0 + g * 8;
          float4 bias = *(const float4*)(b2 + nb);
          float w0 = fmaxf(acc[mt][nt][g * 4 + 0] + bias.x, 0.f);
          float w1 = fmaxf(acc[mt][nt][g * 4 + 1] + bias.y, 0.f);
          float w2 = fmaxf(acc[mt][nt][g * 4 + 2] + bias.z, 0.f);
          float w3 = fmaxf(acc[mt][nt][g * 4 + 3] + bias.w, 0.f);
          uint2 pk; pk.x = pk2(w0, w1); pk.y = pk2(w2, w3);
          *(uint2*)(smem + haddr(m, nb)) = pk;
        }
      }
    }
    __syncthreads();

    // ---- heads (16x16x32): o[m][c] = h2[m] . Hd[:,c], one wave per 16 rows
    {
      const int mrow = wv * 16;
      const v8s* Hp = (const v8s*)Hdp;
      v4f hacc = (v4f)(0.f);
#pragma unroll
      for (int kt = 0; kt < 8; ++kt) {
        v8s a = *(const v8s*)(smem + haddr(mrow + l16, kt * 32 + q * 8));
        v8s b = Hp[kt * 64 + lane];   // coalesced 1KB/wave, L1-hot
        hacc = __builtin_amdgcn_mfma_f32_16x16x32_bf16(a, b, hacc, 0, 0, 0);
      }
      if (l16 < 4) {
#pragma unroll
        for (int r = 0; r < 4; ++r)
          fbH[(mrow + q * 4 + r) * 4 + l16] = hacc[r];
      }
    }
    __syncthreads();

    // ---- volume rendering tail: single wave, shuffle scan
    if (tid < 64) {
      float dw0 = brgb[0] - (rdx * Wrgb[768] + rdy * Wrgb[771] + rdz * Wrgb[774]);
      float dw1 = brgb[1] - (rdx * Wrgb[769] + rdy * Wrgb[772] + rdz * Wrgb[775]);
      float dw2 = brgb[2] - (rdx * Wrgb[770] + rdy * Wrgb[773] + rdz * Wrgb[776]);
      float bs = bsig[0];

      int s0i = tid * 2, s1i = s0i + 1;
      float s0 = fmaxf(fbH[s0i * 4] + bs, 0.f);
      float s1 = fmaxf(fbH[s1i * 4] + bs, 0.f);
      float a0 = 1.0f - __expf(-s0 * DZ);
      float a1 = (s1i == SAMPLES - 1) ? 1.0f : (1.0f - __expf(-s1 * DZ));
      float v0 = 1.0f - a0 + EPSV;
      float v1 = 1.0f - a1 + EPSV;

      float P = v0 * v1;
#pragma unroll
      for (int d = 1; d < 64; d <<= 1) {       // inclusive cumprod over lanes
        float t = __shfl_up(P, d);
        if (tid >= d) P *= t;
      }
      float E = __shfl_up(P, 1);               // exclusive
      if (tid == 0) E = 1.0f;
      float w0 = a0 * E;
      float w1 = a1 * E * v0;

      float dwc[3] = {dw0, dw1, dw2};
      float res[3];
#pragma unroll
      for (int c = 0; c < 3; ++c) {
        float x0 = fbH[s0i * 4 + 1 + c] + dwc[c];
        float x1 = fbH[s1i * 4 + 1 + c] + dwc[c];
        float r0 = 1.0f / (1.0f + __expf(-x0));
        float r1 = 1.0f / (1.0f + __expf(-x1));
        float s = w0 * r0 + w1 * r1;
#pragma unroll
        for (int d = 32; d >= 1; d >>= 1) s += __shfl_xor(s, d);
        res[c] = s;
      }
      if (tid == 0) {
        out[ray * 3 + 0] = res[0];
        out[ray * 3 + 1] = res[1];
        out[ray * 3 + 2] = res[2];
      }
    }
    __syncthreads();   // protect fbH / h1 before next ray overwrites
  }
}

extern "C" void kernel_launch(void* const* d_in, const int* in_sizes, int n_in,
                              void* d_out, int out_size, void* d_ws, size_t ws_size,
                              hipStream_t stream) {
  const float* cam  = (const float*)d_in[0];
  const float* rayv = (const float*)d_in[1];
  const float* W1   = (const float*)d_in[2];
  const float* b1   = (const float*)d_in[3];
  const float* W2   = (const float*)d_in[4];
  const float* b2   = (const float*)d_in[5];
  const float* Wsig = (const float*)d_in[6];
  const float* bsig = (const float*)d_in[7];
  const float* Wrgb = (const float*)d_in[8];
  const float* brgb = (const float*)d_in[9];
  float* out = (float*)d_out;

  unsigned short* W2p = (unsigned short*)d_ws;     // 256*256 bf16 = 128 KB
  unsigned short* Hdp = W2p + 256 * 256;           // 256*16 bf16 = 8 KB

  int R = in_sizes[0] / 3;                         // B*N rays (4096)
  int nblk = 512;
  int rpb = R / nblk;                              // 8 rays per block

  pack<<<34, 256, 0, stream>>>(W2, Wsig, Wrgb, W2p, Hdp);
  render<<<nblk, 512, 0, stream>>>(cam, rayv, W1, b1, b2, bsig, Wrgb, brgb,
                                   W2p, Hdp, out, rpb);
}